// Round 2
// baseline (253.072 us; speedup 1.0000x reference)
//
#include <hip/hip_runtime.h>
#include <math.h>

#define DIM    2048
#define BATCH  256
#define PN     56          // PATCH_NUM - MASK_NUM
#define CHUNK  128         // columns staged in LDS at a time
#define NCHUNK 4           // chunks per block
#define NQ     4           // column-quarters per batch row (DIM / QCOLS)
#define QCOLS  (CHUNK * NCHUNK)   // 512 cols per block
#define NBLK   (BATCH * NQ)       // 1024 blocks
constexpr float KD_T = 4.0f;

// ---------------- reduction helpers (wave = 64) ----------------
__device__ __forceinline__ float wave_sum(float v) {
#pragma unroll
    for (int o = 32; o > 0; o >>= 1) v += __shfl_xor(v, o, 64);
    return v;
}
__device__ __forceinline__ float half_sum(float v) {   // reduce within 32-lane half
#pragma unroll
    for (int o = 16; o > 0; o >>= 1) v += __shfl_xor(v, o, 64);
    return v;
}
__device__ __forceinline__ double wave_sum_d(double v) {
#pragma unroll
    for (int o = 32; o > 0; o >>= 1) v += __shfl_xor(v, o, 64);
    return v;
}

// ---------------- fused bar + dil + dcl (single HBM pass over ebp) ---------
// block = (b, quarter of D). Per 128-col chunk (v3 structure):
//   - next chunk's 7 float4 loads issued BEFORE staging current chunk
//     (HBM latency hides under pass B's exp/VALU work, T14-style)
//   - bar computed per-wave IN REGISTERS from redbar (no bar_s, no t<32
//     stage): 2 barriers/chunk instead of 3
//   - all ebg reads hoisted to g_all[4] at kernel entry; dil is float4 on
//     wave 0 lanes 0..31
// pdcl layout TRANSPOSED for coalesced finalize: [(p*BATCH + b)*NQ + q][4].
// Block 0 thread 0 re-zeros the finalize accumulator + ticket (replay-safe).
__global__ void __launch_bounds__(256, 4) fused_kernel(const float* __restrict__ ebg,
                                                       const float* __restrict__ ebp,
                                                       float* __restrict__ pdcl,
                                                       float* __restrict__ pdil,   // [NBLK][4]
                                                       double* __restrict__ dcl_acc,
                                                       unsigned* __restrict__ ticket)
{
    __shared__ float  ebp_s[PN * CHUNK];   // 28672 B
    __shared__ float4 redbar[4][32];       // 2048 B
    __shared__ float  redl[4][4];

    const int t    = threadIdx.x;
    const int lane = t & 63;
    const int wv   = t >> 6;
    const int sub  = lane >> 5;            // half-wave id
    const int c32  = lane & 31;
    const int bid  = blockIdx.x;
    const int b    = bid >> 2;
    const int q    = bid & (NQ - 1);
    const float invT = 1.0f / KD_T;

    if (bid == 0 && t == 0) { *dcl_acc = 0.0; *ticket = 0u; }  // visible to finalize at dispatch boundary

    const size_t rowoff = (size_t)b * DIM + (size_t)q * QCOLS;

    // hoisted ebg quarter-row: g_all[c] holds cols (c*128 + c32*4 .. +3)
    float4 g_all[NCHUNK];
#pragma unroll
    for (int c = 0; c < NCHUNK; ++c)
        g_all[c] = *(const float4*)(ebg + rowoff + c * CHUNK + c32 * 4);

    float acc[7][4];                        // per-lane; row = wv*14 + 2*j + sub
#pragma unroll
    for (int j = 0; j < 7; ++j)
#pragma unroll
        for (int k = 0; k < 4; ++k) acc[j][k] = 0.f;

    float dss = 0.f, dts = 0.f, dt1 = 0.f, dt2 = 0.f;   // dil (wave 0, lanes<32)

    // staging geometry: thread covers p-rows {it*8 + prow0}, cols cc4..cc4+3
    const int prow0 = t >> 5;              // 0..7
    const int cc4   = (t & 31) * 4;
    const float* pbase = ebp + (size_t)prow0 * (BATCH * DIM) + rowoff + cc4;

    // prologue: chunk 0 loads
    float4 vals[7];
#pragma unroll
    for (int it = 0; it < 7; ++it)
        vals[it] = *(const float4*)(pbase + (size_t)(it * 8) * (BATCH * DIM));

#pragma unroll
    for (int c = 0; c < NCHUNK; ++c) {
        // ---- prefetch chunk c+1 (in flight across pass B) ----
        float4 vnext[7];
        if (c + 1 < NCHUNK) {
#pragma unroll
            for (int it = 0; it < 7; ++it)
                vnext[it] = *(const float4*)(pbase + (size_t)(it * 8) * (BATCH * DIM)
                                             + (c + 1) * CHUNK);
        }

        // ---- stage 56x128 chunk from regs + bar partial ----
        float4 bp = {0.f, 0.f, 0.f, 0.f};
#pragma unroll
        for (int it = 0; it < 7; ++it) {
            const int p = it * 8 + prow0;
            *(float4*)(ebp_s + p * CHUNK + cc4) = vals[it];
            bp.x += vals[it].x; bp.y += vals[it].y;
            bp.z += vals[it].z; bp.w += vals[it].w;
        }
        // combine the two half-waves (rows prow0, prow0+1 across lane^32)
        bp.x += __shfl_xor(bp.x, 32, 64);
        bp.y += __shfl_xor(bp.y, 32, 64);
        bp.z += __shfl_xor(bp.z, 32, 64);
        bp.w += __shfl_xor(bp.w, 32, 64);
        if (sub == 0) redbar[wv][c32] = bp;     // wave w's 14-row partial
        __syncthreads();                        // ebp_s staged + redbar ready

        // ---- bar in registers (each wave combines the 4 partials) ----
        const float4 r0 = redbar[0][c32], r1 = redbar[1][c32],
                     r2 = redbar[2][c32], r3 = redbar[3][c32];
        float4 bar4;
        bar4.x = (r0.x + r1.x + r2.x + r3.x) * (1.0f / PN);
        bar4.y = (r0.y + r1.y + r2.y + r3.y) * (1.0f / PN);
        bar4.z = (r0.z + r1.z + r2.z + r3.z) * (1.0f / PN);
        bar4.w = (r0.w + r1.w + r2.w + r3.w) * (1.0f / PN);

        const float gs[4] = {g_all[c].x, g_all[c].y, g_all[c].z, g_all[c].w};
        const float ms[4] = {bar4.x, bar4.y, bar4.z, bar4.w};

        // ---- dil partials (wave 0, lanes 0..31: 4 columns each) ----
        if (wv == 0 && sub == 0) {
#pragma unroll
            for (int k = 0; k < 4; ++k) {
                float s = gs[k] * invT, tv = ms[k] * invT;
                float es = __expf(s), et = __expf(tv);
                float dd = tv - s;
                dss += es; dts += et;
                dt1 = fmaf(es, dd, dt1);
                dt2 = fmaf(et, dd, dt2);
            }
        }

        // ---- pass B: half-wave per row, 14 rows per wave ----
#pragma unroll
        for (int j = 0; j < 7; ++j) {
            const int row = wv * 14 + 2 * j + sub;
            float4 e = *(const float4*)(ebp_s + row * CHUNK + c32 * 4);
            float es_[4] = {e.x, e.y, e.z, e.w};
#pragma unroll
            for (int k = 0; k < 4; ++k) {
                float dg = gs[k] - es_[k];
                float db = ms[k] - es_[k];
                float a  = dg * dg * invT;
                float cc = db * db * invT;
                float ea = __expf(a), ec = __expf(cc);
                float d  = cc - a;
                acc[j][0] += ea;
                acc[j][1] += ec;
                acc[j][2] = fmaf(ea, d, acc[j][2]);
                acc[j][3] = fmaf(ec, d, acc[j][3]);
            }
        }
        __syncthreads();   // everyone done with ebp_s/redbar before next stage

        if (c + 1 < NCHUNK) {
#pragma unroll
            for (int it = 0; it < 7; ++it) vals[it] = vnext[it];
        }
    }

    // ---- dcl partials: half-wave reductions, lanes 0 & 32 write ----
#pragma unroll
    for (int j = 0; j < 7; ++j) {
        float a0 = half_sum(acc[j][0]);
        float a1 = half_sum(acc[j][1]);
        float a2 = half_sum(acc[j][2]);
        float a3 = half_sum(acc[j][3]);
        if (c32 == 0) {
            const int row = wv * 14 + 2 * j + sub;
            float* qp = pdcl + (((size_t)row * BATCH + b) * NQ + q) * 4;
            qp[0] = a0; qp[1] = a1; qp[2] = a2; qp[3] = a3;
        }
    }
    // ---- dil block reduction (waves 1..3 contribute zeros) ----
    dss = wave_sum(dss); dts = wave_sum(dts);
    dt1 = wave_sum(dt1); dt2 = wave_sum(dt2);
    if (lane == 0) { redl[wv][0] = dss; redl[wv][1] = dts; redl[wv][2] = dt1; redl[wv][3] = dt2; }
    __syncthreads();
    if (t == 0) {
        float* qp = pdil + (size_t)bid * 4;
#pragma unroll
        for (int k = 0; k < 4; ++k)
            qp[k] = redl[0][k] + redl[1][k] + redl[2][k] + redl[3][k];
    }
}

// ---------------- merged finalize: per-p ratios + last-block combine -------
// grid = PN blocks, 256 threads (one per b). pdcl reads fully coalesced.
// Each block atomically adds its per-p dcl partial into *dcl_acc (device-
// scope f64 atomic => coherent across XCDs), then takes a ticket; the last
// block to finish computes the dil combine from pdil and writes out[0..1].
__global__ void __launch_bounds__(256) finalize_kernel(const float* __restrict__ pdcl,
                                                       const float* __restrict__ pdil,
                                                       double* __restrict__ dcl_acc,
                                                       unsigned* __restrict__ ticket,
                                                       float* __restrict__ out)
{
    __shared__ double sd[4];
    __shared__ int win_s;
    const int p = blockIdx.x, t = threadIdx.x, lane = t & 63, wv = t >> 6;

    // ---- per-p dcl partial ----
    const float* base = pdcl + ((size_t)p * BATCH + t) * NQ * 4;
    double A = 0.0, C = 0.0, T1 = 0.0, T2 = 0.0;
#pragma unroll
    for (int qq = 0; qq < NQ; ++qq) {
        float4 v = *(const float4*)(base + qq * 4);
        A += v.x; C += v.y; T1 += v.z; T2 += v.w;
    }
    double r = T2 / C - T1 / A;
    r = wave_sum_d(r);
    if (lane == 0) sd[wv] = r;
    __syncthreads();
    if (t == 0) {
        atomicAdd(dcl_acc, sd[0] + sd[1] + sd[2] + sd[3]);  // device-scope, coherent
        __threadfence();
        unsigned old = atomicAdd(ticket, 1u);
        win_s = (old == PN - 1) ? 1 : 0;
    }
    __syncthreads();
    if (!win_s) return;          // block-uniform exit

    // ---- winner block: dil combine ----
    __threadfence();             // order ticket win before reading dcl_acc
    const float* dbase = pdil + (size_t)t * NQ * 4;   // written by prev dispatch: safe
    double ss = 0.0, ts = 0.0, u1 = 0.0, u2 = 0.0;
#pragma unroll
    for (int qq = 0; qq < NQ; ++qq) {
        float4 v = *(const float4*)(dbase + qq * 4);
        ss += v.x; ts += v.y; u1 += v.z; u2 += v.w;
    }
    double vl = u2 / ts - u1 / ss;
    vl = wave_sum_d(vl);
    if (lane == 0) sd[wv] = vl;  // safe reuse: all threads passed the 2nd barrier
    __syncthreads();
    if (t == 0) {
        double dcl = atomicAdd(dcl_acc, 0.0);   // coherent read of the full sum
        const double kT2 = (double)KD_T * KD_T;
        out[0] = (float)((sd[0] + sd[1] + sd[2] + sd[3]) * (kT2 / DIM));
        out[1] = (float)(dcl * (kT2 / DIM / PN));
    }
}

extern "C" void kernel_launch(void* const* d_in, const int* in_sizes, int n_in,
                              void* d_out, int out_size, void* d_ws, size_t ws_size,
                              hipStream_t stream) {
    const float* ebg = (const float*)d_in[0];
    const float* ebp = (const float*)d_in[1];
    // labels (d_in[2]) unused by the forward computation

    float*    pdcl    = (float*)d_ws;                                 // PN*BATCH*NQ*4 floats = 896 KB
    float*    pdil    = pdcl + (size_t)PN * BATCH * NQ * 4;           // NBLK*4 floats = 16 KB
    double*   dcl_acc = (double*)(pdil + (size_t)NBLK * 4);           // 8 B (8-aligned)
    unsigned* ticket  = (unsigned*)(dcl_acc + 1);                     // 4 B

    fused_kernel<<<NBLK, 256, 0, stream>>>(ebg, ebp, pdcl, pdil, dcl_acc, ticket);
    finalize_kernel<<<PN, 256, 0, stream>>>(pdcl, pdil, dcl_acc, ticket, (float*)d_out);
}

// Round 3
// 189.954 us; speedup vs baseline: 1.3323x; 1.3323x over previous
//
#include <hip/hip_runtime.h>
#include <math.h>

#define DIM    2048
#define BATCH  256
#define PN     56          // PATCH_NUM - MASK_NUM
#define CHUNK  128         // columns staged in LDS at a time
#define NCHUNK 4           // chunks per block
#define NQ     4           // column-quarters per batch row (DIM / QCOLS)
#define QCOLS  (CHUNK * NCHUNK)   // 512 cols per block
#define NBLK   (BATCH * NQ)       // 1024 blocks
constexpr float KD_T = 4.0f;

// ---------------- reduction helpers (wave = 64) ----------------
__device__ __forceinline__ float wave_sum(float v) {
#pragma unroll
    for (int o = 32; o > 0; o >>= 1) v += __shfl_xor(v, o, 64);
    return v;
}
__device__ __forceinline__ float half_sum(float v) {   // reduce within 32-lane half
#pragma unroll
    for (int o = 16; o > 0; o >>= 1) v += __shfl_xor(v, o, 64);
    return v;
}
__device__ __forceinline__ double wave_sum_d(double v) {
#pragma unroll
    for (int o = 32; o > 0; o >>= 1) v += __shfl_xor(v, o, 64);
    return v;
}

// ---------------- fused bar + dil + dcl (single HBM pass over ebp) ---------
// block = (b, quarter of D). Per 128-col chunk (v4 structure):
//   - SINGLE-buffer load rotation: after staging chunk c's vals[] to LDS,
//     the SAME 7 float4 registers are refilled with chunk c+1's loads
//     (WAR dep orders them after the ds_writes); loads stay in flight
//     across pass B's exp/VALU work. No extra VGPRs — R2's spill
//     (WRITE_SIZE 148 MB of scratch) came from double-buffering vnext[7]
//     under a launch_bounds VGPR cap; both removed.
//   - bar combined per-wave IN REGISTERS from redbar: 2 barriers/chunk
//   - ebg hoisted to g_all[4] at entry; dil is float4 on wave 0 lanes<32
// pdcl layout TRANSPOSED for coalesced finalize: [(p*BATCH + b)*NQ + q][4].
// Block 0 thread 0 re-zeros the finalize accumulator + ticket (replay-safe).
__global__ void __launch_bounds__(256) fused_kernel(const float* __restrict__ ebg,
                                                    const float* __restrict__ ebp,
                                                    float* __restrict__ pdcl,
                                                    float* __restrict__ pdil,   // [NBLK][4]
                                                    double* __restrict__ dcl_acc,
                                                    unsigned* __restrict__ ticket)
{
    __shared__ float  ebp_s[PN * CHUNK];   // 28672 B
    __shared__ float4 redbar[4][32];       // 2048 B
    __shared__ float  redl[4][4];

    const int t    = threadIdx.x;
    const int lane = t & 63;
    const int wv   = t >> 6;
    const int sub  = lane >> 5;            // half-wave id
    const int c32  = lane & 31;
    const int bid  = blockIdx.x;
    const int b    = bid >> 2;
    const int q    = bid & (NQ - 1);
    const float invT = 1.0f / KD_T;

    if (bid == 0 && t == 0) { *dcl_acc = 0.0; *ticket = 0u; }  // visible to finalize at dispatch boundary

    const size_t rowoff = (size_t)b * DIM + (size_t)q * QCOLS;

    // hoisted ebg quarter-row: g_all[c] holds cols (c*128 + c32*4 .. +3)
    float4 g_all[NCHUNK];
#pragma unroll
    for (int c = 0; c < NCHUNK; ++c)
        g_all[c] = *(const float4*)(ebg + rowoff + c * CHUNK + c32 * 4);

    float acc[7][4];                        // per-lane; row = wv*14 + 2*j + sub
#pragma unroll
    for (int j = 0; j < 7; ++j)
#pragma unroll
        for (int k = 0; k < 4; ++k) acc[j][k] = 0.f;

    float dss = 0.f, dts = 0.f, dt1 = 0.f, dt2 = 0.f;   // dil (wave 0, lanes<32)

    // staging geometry: thread covers p-rows {it*8 + prow0}, cols cc4..cc4+3
    const int prow0 = t >> 5;              // 0..7
    const int cc4   = (t & 31) * 4;
    const float* pbase = ebp + (size_t)prow0 * (BATCH * DIM) + rowoff + cc4;

    // prologue: chunk 0 loads
    float4 vals[7];
#pragma unroll
    for (int it = 0; it < 7; ++it)
        vals[it] = *(const float4*)(pbase + (size_t)(it * 8) * (BATCH * DIM));

#pragma unroll
    for (int c = 0; c < NCHUNK; ++c) {
        // ---- stage 56x128 chunk from regs + bar partial ----
        float4 bp = {0.f, 0.f, 0.f, 0.f};
#pragma unroll
        for (int it = 0; it < 7; ++it) {
            const int p = it * 8 + prow0;
            *(float4*)(ebp_s + p * CHUNK + cc4) = vals[it];
            bp.x += vals[it].x; bp.y += vals[it].y;
            bp.z += vals[it].z; bp.w += vals[it].w;
        }

        // ---- refill the SAME registers with chunk c+1 (in flight during
        //      pass B; WAR dep places these after the ds_writes above) ----
        if (c + 1 < NCHUNK) {
#pragma unroll
            for (int it = 0; it < 7; ++it)
                vals[it] = *(const float4*)(pbase + (size_t)(it * 8) * (BATCH * DIM)
                                            + (size_t)(c + 1) * CHUNK);
        }

        // combine the two half-waves (rows prow0, prow0+1 across lane^32)
        bp.x += __shfl_xor(bp.x, 32, 64);
        bp.y += __shfl_xor(bp.y, 32, 64);
        bp.z += __shfl_xor(bp.z, 32, 64);
        bp.w += __shfl_xor(bp.w, 32, 64);
        if (sub == 0) redbar[wv][c32] = bp;     // wave w's 14-row partial
        __syncthreads();                        // ebp_s staged + redbar ready

        // ---- bar in registers (each wave combines the 4 partials) ----
        const float4 r0 = redbar[0][c32], r1 = redbar[1][c32],
                     r2 = redbar[2][c32], r3 = redbar[3][c32];
        float4 bar4;
        bar4.x = (r0.x + r1.x + r2.x + r3.x) * (1.0f / PN);
        bar4.y = (r0.y + r1.y + r2.y + r3.y) * (1.0f / PN);
        bar4.z = (r0.z + r1.z + r2.z + r3.z) * (1.0f / PN);
        bar4.w = (r0.w + r1.w + r2.w + r3.w) * (1.0f / PN);

        const float gs[4] = {g_all[c].x, g_all[c].y, g_all[c].z, g_all[c].w};
        const float ms[4] = {bar4.x, bar4.y, bar4.z, bar4.w};

        // ---- dil partials (wave 0, lanes 0..31: 4 columns each) ----
        if (wv == 0 && sub == 0) {
#pragma unroll
            for (int k = 0; k < 4; ++k) {
                float s = gs[k] * invT, tv = ms[k] * invT;
                float es = __expf(s), et = __expf(tv);
                float dd = tv - s;
                dss += es; dts += et;
                dt1 = fmaf(es, dd, dt1);
                dt2 = fmaf(et, dd, dt2);
            }
        }

        // ---- pass B: half-wave per row, 14 rows per wave ----
#pragma unroll
        for (int j = 0; j < 7; ++j) {
            const int row = wv * 14 + 2 * j + sub;
            float4 e = *(const float4*)(ebp_s + row * CHUNK + c32 * 4);
            float es_[4] = {e.x, e.y, e.z, e.w};
#pragma unroll
            for (int k = 0; k < 4; ++k) {
                float dg = gs[k] - es_[k];
                float db = ms[k] - es_[k];
                float a  = dg * dg * invT;
                float cc = db * db * invT;
                float ea = __expf(a), ec = __expf(cc);
                float d  = cc - a;
                acc[j][0] += ea;
                acc[j][1] += ec;
                acc[j][2] = fmaf(ea, d, acc[j][2]);
                acc[j][3] = fmaf(ec, d, acc[j][3]);
            }
        }
        __syncthreads();   // everyone done with ebp_s/redbar before next stage
    }

    // ---- dcl partials: half-wave reductions, lanes 0 & 32 write ----
#pragma unroll
    for (int j = 0; j < 7; ++j) {
        float a0 = half_sum(acc[j][0]);
        float a1 = half_sum(acc[j][1]);
        float a2 = half_sum(acc[j][2]);
        float a3 = half_sum(acc[j][3]);
        if (c32 == 0) {
            const int row = wv * 14 + 2 * j + sub;
            float* qp = pdcl + (((size_t)row * BATCH + b) * NQ + q) * 4;
            qp[0] = a0; qp[1] = a1; qp[2] = a2; qp[3] = a3;
        }
    }
    // ---- dil block reduction (waves 1..3 contribute zeros) ----
    dss = wave_sum(dss); dts = wave_sum(dts);
    dt1 = wave_sum(dt1); dt2 = wave_sum(dt2);
    if (lane == 0) { redl[wv][0] = dss; redl[wv][1] = dts; redl[wv][2] = dt1; redl[wv][3] = dt2; }
    __syncthreads();
    if (t == 0) {
        float* qp = pdil + (size_t)bid * 4;
#pragma unroll
        for (int k = 0; k < 4; ++k)
            qp[k] = redl[0][k] + redl[1][k] + redl[2][k] + redl[3][k];
    }
}

// ---------------- merged finalize: per-p ratios + last-block combine -------
// grid = PN blocks, 256 threads (one per b). pdcl reads fully coalesced.
// Each block atomically adds its per-p dcl partial into *dcl_acc (device-
// scope f64 atomic => coherent across XCDs), then takes a ticket; the last
// block to finish computes the dil combine from pdil and writes out[0..1].
__global__ void __launch_bounds__(256) finalize_kernel(const float* __restrict__ pdcl,
                                                       const float* __restrict__ pdil,
                                                       double* __restrict__ dcl_acc,
                                                       unsigned* __restrict__ ticket,
                                                       float* __restrict__ out)
{
    __shared__ double sd[4];
    __shared__ int win_s;
    const int p = blockIdx.x, t = threadIdx.x, lane = t & 63, wv = t >> 6;

    // ---- per-p dcl partial ----
    const float* base = pdcl + ((size_t)p * BATCH + t) * NQ * 4;
    double A = 0.0, C = 0.0, T1 = 0.0, T2 = 0.0;
#pragma unroll
    for (int qq = 0; qq < NQ; ++qq) {
        float4 v = *(const float4*)(base + qq * 4);
        A += v.x; C += v.y; T1 += v.z; T2 += v.w;
    }
    double r = T2 / C - T1 / A;
    r = wave_sum_d(r);
    if (lane == 0) sd[wv] = r;
    __syncthreads();
    if (t == 0) {
        atomicAdd(dcl_acc, sd[0] + sd[1] + sd[2] + sd[3]);  // device-scope, coherent
        __threadfence();
        unsigned old = atomicAdd(ticket, 1u);
        win_s = (old == PN - 1) ? 1 : 0;
    }
    __syncthreads();
    if (!win_s) return;          // block-uniform exit

    // ---- winner block: dil combine ----
    __threadfence();             // order ticket win before reading dcl_acc
    const float* dbase = pdil + (size_t)t * NQ * 4;   // written by prev dispatch: safe
    double ss = 0.0, ts = 0.0, u1 = 0.0, u2 = 0.0;
#pragma unroll
    for (int qq = 0; qq < NQ; ++qq) {
        float4 v = *(const float4*)(dbase + qq * 4);
        ss += v.x; ts += v.y; u1 += v.z; u2 += v.w;
    }
    double vl = u2 / ts - u1 / ss;
    vl = wave_sum_d(vl);
    if (lane == 0) sd[wv] = vl;  // safe reuse: all threads passed the 2nd barrier
    __syncthreads();
    if (t == 0) {
        double dcl = atomicAdd(dcl_acc, 0.0);   // coherent read of the full sum
        const double kT2 = (double)KD_T * KD_T;
        out[0] = (float)((sd[0] + sd[1] + sd[2] + sd[3]) * (kT2 / DIM));
        out[1] = (float)(dcl * (kT2 / DIM / PN));
    }
}

extern "C" void kernel_launch(void* const* d_in, const int* in_sizes, int n_in,
                              void* d_out, int out_size, void* d_ws, size_t ws_size,
                              hipStream_t stream) {
    const float* ebg = (const float*)d_in[0];
    const float* ebp = (const float*)d_in[1];
    // labels (d_in[2]) unused by the forward computation

    float*    pdcl    = (float*)d_ws;                                 // PN*BATCH*NQ*4 floats = 896 KB
    float*    pdil    = pdcl + (size_t)PN * BATCH * NQ * 4;           // NBLK*4 floats = 16 KB
    double*   dcl_acc = (double*)(pdil + (size_t)NBLK * 4);           // 8 B (8-aligned)
    unsigned* ticket  = (unsigned*)(dcl_acc + 1);                     // 4 B

    fused_kernel<<<NBLK, 256, 0, stream>>>(ebg, ebp, pdcl, pdil, dcl_acc, ticket);
    finalize_kernel<<<PN, 256, 0, stream>>>(pdcl, pdil, dcl_acc, ticket, (float*)d_out);
}

// Round 4
// 182.223 us; speedup vs baseline: 1.3888x; 1.0424x over previous
//
#include <hip/hip_runtime.h>
#include <math.h>

#define DIM    2048
#define BATCH  256
#define PN     56          // PATCH_NUM - MASK_NUM
#define CHUNK  128         // columns staged in LDS at a time
#define NCHUNK 4           // chunks per block
#define NQ     4           // column-quarters per batch row (DIM / QCOLS)
#define QCOLS  (CHUNK * NCHUNK)   // 512 cols per block
#define NBLK   (BATCH * NQ)       // 1024 blocks
constexpr float KD_T = 4.0f;

// Best-measured configuration (182.2 us). R1 (merged finalize via
// atomic+ticket): 183.4. R2 (reg double-buffer + launch_bounds(256,4)):
// 253 — scratch spill, WRITE_SIZE 148 MB. R3 (single-buffer refill
// rotation + register-bar + hoisted ebg): 190 — vmcnt(0) before next
// chunk's ds_writes serializes against loads issued a phase earlier, and
// per-thread bar reads cost more than the t<32 stage they replaced.
// Conclusion: this schedule (load->stage->barrier->compute, 4-5 blocks/CU
// TLP doing the latency hiding) is the structural optimum for the fused
// pass; remaining session time is harness fill kernels at 87% HBM peak.

// ---------------- reduction helpers (wave = 64) ----------------
__device__ __forceinline__ float wave_sum(float v) {
#pragma unroll
    for (int o = 32; o > 0; o >>= 1) v += __shfl_xor(v, o, 64);
    return v;
}
__device__ __forceinline__ float half_sum(float v) {   // reduce within 32-lane half
#pragma unroll
    for (int o = 16; o > 0; o >>= 1) v += __shfl_xor(v, o, 64);
    return v;
}
__device__ __forceinline__ double wave_sum_d(double v) {
#pragma unroll
    for (int o = 32; o > 0; o >>= 1) v += __shfl_xor(v, o, 64);
    return v;
}

// ---------------- fused bar + dil + dcl (single HBM pass over ebp) ---------
// block = (b, quarter of D). Per 128-col chunk:
//   pass A: float4 staging, 8 p-rows per instruction, 7 loads in flight;
//           bar via lane^32 shuffle + 4-wave LDS combine.
//   pass B: half-wave per p-row (2 rows per wave per ds_read_b128; row
//           stride 512 B => 2-way bank aliasing = free). acc[7][4] regs.
// pdcl layout TRANSPOSED for coalesced finalize: [(p*BATCH + b)*NQ + q][4].
__global__ void __launch_bounds__(256) fused_kernel(const float* __restrict__ ebg,
                                                    const float* __restrict__ ebp,
                                                    float* __restrict__ pdcl,
                                                    float* __restrict__ pdil)  // [NBLK][4]
{
    __shared__ float  ebp_s[PN * CHUNK];   // 28672 B
    __shared__ float4 redbar[4][32];       // 2048 B
    __shared__ float  bar_s[CHUNK];        // 512 B
    __shared__ float  redl[4][4];

    const int t    = threadIdx.x;
    const int lane = t & 63;
    const int wv   = t >> 6;
    const int sub  = lane >> 5;            // half-wave id
    const int c32  = lane & 31;
    const int bid  = blockIdx.x;
    const int b    = bid >> 2;
    const int q    = bid & (NQ - 1);
    const float invT = 1.0f / KD_T;

    const size_t rowoff = (size_t)b * DIM + (size_t)q * QCOLS;

    float acc[7][4];                        // per-lane; row = wv*14 + 2*j + sub
#pragma unroll
    for (int j = 0; j < 7; ++j)
#pragma unroll
        for (int k = 0; k < 4; ++k) acc[j][k] = 0.f;

    float dss = 0.f, dts = 0.f, dt1 = 0.f, dt2 = 0.f;   // dil (threads t<128)

    for (int c = 0; c < NCHUNK; ++c) {
        const size_t cb = rowoff + (size_t)c * CHUNK;

        // ---- pass A: stage 56x128 chunk, 8 rows per instruction ----
        const int prow0 = t >> 5;          // 0..7
        const int cc4   = (t & 31) * 4;
        float4 vals[7];
#pragma unroll
        for (int it = 0; it < 7; ++it) {
            const int p = it * 8 + prow0;
            vals[it] = *(const float4*)(ebp + (size_t)p * (BATCH * DIM) + cb + cc4);
        }
        float4 bp = {0.f, 0.f, 0.f, 0.f};
#pragma unroll
        for (int it = 0; it < 7; ++it) {
            const int p = it * 8 + prow0;
            *(float4*)(ebp_s + p * CHUNK + cc4) = vals[it];
            bp.x += vals[it].x; bp.y += vals[it].y;
            bp.z += vals[it].z; bp.w += vals[it].w;
        }
        // combine the two half-waves (rows p and p+1 alternate across lane^32)
        bp.x += __shfl_xor(bp.x, 32, 64);
        bp.y += __shfl_xor(bp.y, 32, 64);
        bp.z += __shfl_xor(bp.z, 32, 64);
        bp.w += __shfl_xor(bp.w, 32, 64);
        if (lane < 32) redbar[wv][lane] = bp;
        __syncthreads();
        if (t < 32) {
            float4 s0 = redbar[0][t], s1 = redbar[1][t],
                   s2 = redbar[2][t], s3 = redbar[3][t];
            float4 s;
            s.x = (s0.x + s1.x + s2.x + s3.x) * (1.0f / PN);
            s.y = (s0.y + s1.y + s2.y + s3.y) * (1.0f / PN);
            s.z = (s0.z + s1.z + s2.z + s3.z) * (1.0f / PN);
            s.w = (s0.w + s1.w + s2.w + s3.w) * (1.0f / PN);
            *(float4*)(bar_s + t * 4) = s;
        }
        __syncthreads();

        // ---- dil partials (threads 0..127, one column each) ----
        if (t < CHUNK) {
            float g = ebg[cb + t];
            float m = bar_s[t];
            float s = g * invT, tv = m * invT;
            float es = __expf(s), et = __expf(tv);
            float dd = tv - s;
            dss += es; dts += et;
            dt1 = fmaf(es, dd, dt1);
            dt2 = fmaf(et, dd, dt2);
        }

        // ---- pass B: half-wave per row, 14 rows per wave ----
        const float4 g4 = *(const float4*)(ebg + cb + c32 * 4);
        const float4 m4 = *(const float4*)(bar_s + c32 * 4);
        const float gs[4] = {g4.x, g4.y, g4.z, g4.w};
        const float ms[4] = {m4.x, m4.y, m4.z, m4.w};
#pragma unroll
        for (int j = 0; j < 7; ++j) {
            const int row = wv * 14 + 2 * j + sub;
            float4 e = *(const float4*)(ebp_s + row * CHUNK + c32 * 4);
            float es_[4] = {e.x, e.y, e.z, e.w};
#pragma unroll
            for (int k = 0; k < 4; ++k) {
                float dg = gs[k] - es_[k];
                float db = ms[k] - es_[k];
                float a  = dg * dg * invT;
                float cc = db * db * invT;
                float ea = __expf(a), ec = __expf(cc);
                float d  = cc - a;
                acc[j][0] += ea;
                acc[j][1] += ec;
                acc[j][2] = fmaf(ea, d, acc[j][2]);
                acc[j][3] = fmaf(ec, d, acc[j][3]);
            }
        }
        __syncthreads();   // protect ebp_s/bar_s before next chunk's staging
    }

    // ---- dcl partials: half-wave reductions, lanes 0 & 32 write ----
#pragma unroll
    for (int j = 0; j < 7; ++j) {
        float a0 = half_sum(acc[j][0]);
        float a1 = half_sum(acc[j][1]);
        float a2 = half_sum(acc[j][2]);
        float a3 = half_sum(acc[j][3]);
        if (c32 == 0) {
            const int row = wv * 14 + 2 * j + sub;
            float* qp = pdcl + (((size_t)row * BATCH + b) * NQ + q) * 4;
            qp[0] = a0; qp[1] = a1; qp[2] = a2; qp[3] = a3;
        }
    }
    // ---- dil block reduction (waves 2,3 contribute zeros) ----
    dss = wave_sum(dss); dts = wave_sum(dts);
    dt1 = wave_sum(dt1); dt2 = wave_sum(dt2);
    if (lane == 0) { redl[wv][0] = dss; redl[wv][1] = dts; redl[wv][2] = dt1; redl[wv][3] = dt2; }
    __syncthreads();
    if (t == 0) {
        float* qp = pdil + (size_t)bid * 4;
#pragma unroll
        for (int k = 0; k < 4; ++k)
            qp[k] = redl[0][k] + redl[1][k] + redl[2][k] + redl[3][k];
    }
}

// ---------------- finalize 1: per-(b,p) ratios, reduced per p-block --------
// grid = PN blocks, 256 threads (one per b). pdcl reads are fully coalesced:
// thread b reads 64 consecutive bytes at ((p*BATCH+b)*NQ)*16.
__global__ void __launch_bounds__(256) finalize1_kernel(const float* __restrict__ pdcl,
                                                        double* __restrict__ partial)
{
    __shared__ double sd[4];
    const int p = blockIdx.x, t = threadIdx.x, lane = t & 63, wv = t >> 6;
    const float* base = pdcl + ((size_t)p * BATCH + t) * NQ * 4;
    double A = 0.0, C = 0.0, T1 = 0.0, T2 = 0.0;
#pragma unroll
    for (int qq = 0; qq < NQ; ++qq) {
        float4 v = *(const float4*)(base + qq * 4);
        A += v.x; C += v.y; T1 += v.z; T2 += v.w;
    }
    double r = T2 / C - T1 / A;
    r = wave_sum_d(r);
    if (lane == 0) sd[wv] = r;
    __syncthreads();
    if (t == 0) partial[p] = sd[0] + sd[1] + sd[2] + sd[3];
}

// ---------------- finalize 2: combine p-partials + dil, emit outputs ------
__global__ void __launch_bounds__(256) finalize2_kernel(const double* __restrict__ partial,
                                                        const float* __restrict__ pdil,
                                                        float* __restrict__ out)
{
    __shared__ double sdc[4], sdl[4];
    const int t = threadIdx.x, lane = t & 63, wv = t >> 6;

    // dcl: sum the 56 per-p partials
    double vd = (t < PN) ? partial[t] : 0.0;

    // dil: thread t owns batch row b=t; combine NQ quarter-sums then ratio
    const float* base = pdil + (size_t)t * NQ * 4;
    double ss = 0.0, ts = 0.0, u1 = 0.0, u2 = 0.0;
#pragma unroll
    for (int qq = 0; qq < NQ; ++qq) {
        float4 v = *(const float4*)(base + qq * 4);
        ss += v.x; ts += v.y; u1 += v.z; u2 += v.w;
    }
    double vl = u2 / ts - u1 / ss;

    vd = wave_sum_d(vd); vl = wave_sum_d(vl);
    if (lane == 0) { sdc[wv] = vd; sdl[wv] = vl; }
    __syncthreads();
    if (t == 0) {
        const double kT2 = (double)KD_T * KD_T;
        out[0] = (float)((sdl[0] + sdl[1] + sdl[2] + sdl[3]) * (kT2 / DIM));
        out[1] = (float)((sdc[0] + sdc[1] + sdc[2] + sdc[3]) * (kT2 / DIM / PN));
    }
}

extern "C" void kernel_launch(void* const* d_in, const int* in_sizes, int n_in,
                              void* d_out, int out_size, void* d_ws, size_t ws_size,
                              hipStream_t stream) {
    const float* ebg = (const float*)d_in[0];
    const float* ebp = (const float*)d_in[1];
    // labels (d_in[2]) unused by the forward computation

    float*  pdcl    = (float*)d_ws;                                   // PN*BATCH*NQ*4 floats = 896 KB
    float*  pdil    = pdcl + (size_t)PN * BATCH * NQ * 4;             // NBLK*4 floats = 16 KB
    double* partial = (double*)(pdil + (size_t)NBLK * 4);             // PN doubles

    fused_kernel<<<NBLK, 256, 0, stream>>>(ebg, ebp, pdcl, pdil);
    finalize1_kernel<<<PN, 256, 0, stream>>>(pdcl, partial);
    finalize2_kernel<<<1, 256, 0, stream>>>(partial, pdil, (float*)d_out);
}